// Round 10
// baseline (382.340 us; speedup 1.0000x reference)
//
#include <hip/hip_runtime.h>
#include <hip/hip_fp16.h>
#include <stdint.h>

#define BB 512
#define TT 1024
#define II 15
#define HH 64
#define OO 11

typedef __fp16 half2v __attribute__((ext_vector_type(2)));
typedef _Float16 half8 __attribute__((ext_vector_type(8)));
typedef float floatx4 __attribute__((ext_vector_type(4)));
typedef int int4v __attribute__((ext_vector_type(4)));

union PK { int i; half2v h; float f; };

__device__ __forceinline__ half2v i2h2(int v) { PK u; u.i = v; return u.h; }
__device__ __forceinline__ int h22i(half2v v) { PK u; u.h = v; return u.i; }

__device__ __forceinline__ float FDOT2(half2v a, half2v b, float c) {
    return __builtin_amdgcn_fdot2(a, b, c, false);
}

// TWO chains per wave, PHASE-SHIFTED (not lockstep like R9): while chain A's
// LDS round trip (h-write -> 8 broadcast b128 reads, ~230 cyc) is in flight,
// the wave executes chain B's entire dot block, and vice versa. DS returns
// in order, so the compiler's fine-grained lgkmcnt(N) lets A's dots start
// while B's just-issued reads are still outstanding.
// Per phase (one chain's step): 8 xproj dots + 32 GEMV dots + tree/relu +
// ds_write_b16 + 8 b128 h-reads + 2 b128 x-reads + 1 global b16 store.
// W_hh/W_ih register copies are SHARED between the chains.
__global__ __launch_bounds__(64) void rnn_rec(
    const float* __restrict__ x, const float* __restrict__ W_ih,
    const float* __restrict__ b_ih, const float* __restrict__ W_hh,
    const float* __restrict__ b_hh, _Float16* __restrict__ hs,
    float* __restrict__ h_last)
{
    __shared__ __align__(16) int xbuf[2][2][64 * 8]; // [chain][dbl][step*8]
    __shared__ __align__(16) _Float16 hbuf[2][64];   // [chain][h]
    const int lane = threadIdx.x;
    const int b0 = blockIdx.x * 2;

    // shared weights: whh[p] = (W_hh[lane][2p], W_hh[lane][2p+1])
    half2v whh[32];
#pragma unroll
    for (int p = 0; p < 32; ++p)
        whh[p] = __builtin_amdgcn_cvt_pkrtz(W_hh[lane * HH + 2 * p],
                                            W_hh[lane * HH + 2 * p + 1]);
    // input weights; pair 7 = (w14, bias) matching x pair (x14, 1.0)
    half2v wx[8];
#pragma unroll
    for (int j = 0; j < 7; ++j)
        wx[j] = __builtin_amdgcn_cvt_pkrtz(W_ih[lane * II + 2 * j],
                                           W_ih[lane * II + 2 * j + 1]);
    wx[7] = __builtin_amdgcn_cvt_pkrtz(W_ih[lane * II + 14],
                                       b_ih[lane] + b_hh[lane]);

    const float* xb0 = x + (size_t)b0 * TT * II;
    const float* xb1 = x + (size_t)(b0 + 1) * TT * II;
    _Float16* hr0 = hs + (size_t)b0 * TT * HH + lane;
    _Float16* hr1 = hs + (size_t)(b0 + 1) * TT * HH + lane;

    // stage chunk 0 for both chains: lane ts packs x[bq][ts][0..14] -> 8 pairs
#pragma unroll
    for (int q = 0; q < 2; ++q) {
        const float* xq = q ? xb1 : xb0;
        float cf[II];
#pragma unroll
        for (int i = 0; i < II; ++i) cf[i] = xq[lane * II + i];
        int4v p0, p1;
        p0.x = h22i(__builtin_amdgcn_cvt_pkrtz(cf[0], cf[1]));
        p0.y = h22i(__builtin_amdgcn_cvt_pkrtz(cf[2], cf[3]));
        p0.z = h22i(__builtin_amdgcn_cvt_pkrtz(cf[4], cf[5]));
        p0.w = h22i(__builtin_amdgcn_cvt_pkrtz(cf[6], cf[7]));
        p1.x = h22i(__builtin_amdgcn_cvt_pkrtz(cf[8], cf[9]));
        p1.y = h22i(__builtin_amdgcn_cvt_pkrtz(cf[10], cf[11]));
        p1.z = h22i(__builtin_amdgcn_cvt_pkrtz(cf[12], cf[13]));
        p1.w = h22i(__builtin_amdgcn_cvt_pkrtz(cf[14], 1.0f));
        *(int4v*)&xbuf[q][0][lane * 8] = p0;
        *(int4v*)&xbuf[q][0][lane * 8 + 4] = p1;
    }
    hbuf[0][lane] = (_Float16)0.0f;   // h(-1) = 0
    hbuf[1][lane] = (_Float16)0.0f;

    // in-flight state per chain: hb (h broadcast regs) + xv (x pair regs)
    int4v hbA[8], hbB[8], xvA0, xvA1, xvB0, xvB1;
#pragma unroll
    for (int i = 0; i < 8; ++i) hbA[i] = ((const int4v*)hbuf[0])[i];
    xvA0 = *(const int4v*)&xbuf[0][0][0];
    xvA1 = *(const int4v*)&xbuf[0][0][4];
#pragma unroll
    for (int i = 0; i < 8; ++i) hbB[i] = ((const int4v*)hbuf[1])[i];
    xvB0 = *(const int4v*)&xbuf[1][0][0];
    xvB1 = *(const int4v*)&xbuf[1][0][4];

    float hA = 0.0f, hB = 0.0f;

    auto phase = [&](int q, int4v (&hb)[8], int4v& xv0, int4v& xv1,
                     float& h, _Float16* hr, int t) {
        // xproj seeds from xv (issued one full cycle ago -> ready)
        float a0 = FDOT2(i2h2(xv0.x), wx[0], 0.0f);
        float a1 = FDOT2(i2h2(xv0.y), wx[1], 0.0f);
        float a2 = FDOT2(i2h2(xv0.z), wx[2], 0.0f);
        float a3 = FDOT2(i2h2(xv0.w), wx[3], 0.0f);
        float a4 = FDOT2(i2h2(xv1.x), wx[4], 0.0f);
        float a5 = FDOT2(i2h2(xv1.y), wx[5], 0.0f);
        float a6 = FDOT2(i2h2(xv1.z), wx[6], 0.0f);
        float a7 = FDOT2(i2h2(xv1.w), wx[7], 0.0f);
        // GEMV: 8 chains x depth 4 on the in-flight broadcast regs
#pragma unroll
        for (int r = 0; r < 4; ++r) {
            a0 = FDOT2(i2h2(hb[2 * r].x),     whh[8 * r + 0], a0);
            a1 = FDOT2(i2h2(hb[2 * r].y),     whh[8 * r + 1], a1);
            a2 = FDOT2(i2h2(hb[2 * r].z),     whh[8 * r + 2], a2);
            a3 = FDOT2(i2h2(hb[2 * r].w),     whh[8 * r + 3], a3);
            a4 = FDOT2(i2h2(hb[2 * r + 1].x), whh[8 * r + 4], a4);
            a5 = FDOT2(i2h2(hb[2 * r + 1].y), whh[8 * r + 5], a5);
            a6 = FDOT2(i2h2(hb[2 * r + 1].z), whh[8 * r + 6], a6);
            a7 = FDOT2(i2h2(hb[2 * r + 1].w), whh[8 * r + 7], a7);
        }
        h = fmaxf(((a0 + a1) + (a2 + a3)) + ((a4 + a5) + (a6 + a7)), 0.0f);
        const _Float16 hf = (_Float16)h;
        hbuf[q][lane] = hf;                    // publish h(t)
        // reads for t+1, right behind the write in the in-order DS pipe;
        // they stay in flight while the OTHER chain's phase computes
#pragma unroll
        for (int i = 0; i < 8; ++i) hb[i] = ((const int4v*)hbuf[q])[i];
        const int tn = t + 1;
        const int* xp = &xbuf[q][(tn >> 6) & 1][(tn & 63) * 8];
        xv0 = *(const int4v*)xp;
        xv1 = *(const int4v*)(xp + 4);
        hr[(size_t)t * HH] = hf;               // 128B contiguous global store
    };

    for (int tc = 0; tc < TT; tc += 64) {
        // global prefetch of both chains' next chunk
        const int tnb = (tc + 64 < TT) ? (tc + 64) : tc;
        float nf0[II], nf1[II];
#pragma unroll
        for (int i = 0; i < II; ++i)
            nf0[i] = xb0[(size_t)(tnb + lane) * II + i];
#pragma unroll
        for (int i = 0; i < II; ++i)
            nf1[i] = xb1[(size_t)(tnb + lane) * II + i];

        for (int to = 0; to < 32; to += 4)
#pragma unroll
            for (int u = 0; u < 4; ++u) {
                const int t = tc + to + u;
                phase(0, hbA, xvA0, xvA1, hA, hr0, t);
                phase(1, hbB, xvB0, xvB1, hB, hr1, t);
            }

        // commit prefetched chunks into the other xbuf half (first read of
        // that half happens at t = tc+63 for t+1 = tc+64)
        {
            const int cb = ((tc >> 6) + 1) & 1;
#pragma unroll
            for (int q = 0; q < 2; ++q) {
                const float* nf = q ? nf1 : nf0;
                int4v p0, p1;
                p0.x = h22i(__builtin_amdgcn_cvt_pkrtz(nf[0], nf[1]));
                p0.y = h22i(__builtin_amdgcn_cvt_pkrtz(nf[2], nf[3]));
                p0.z = h22i(__builtin_amdgcn_cvt_pkrtz(nf[4], nf[5]));
                p0.w = h22i(__builtin_amdgcn_cvt_pkrtz(nf[6], nf[7]));
                p1.x = h22i(__builtin_amdgcn_cvt_pkrtz(nf[8], nf[9]));
                p1.y = h22i(__builtin_amdgcn_cvt_pkrtz(nf[10], nf[11]));
                p1.z = h22i(__builtin_amdgcn_cvt_pkrtz(nf[12], nf[13]));
                p1.w = h22i(__builtin_amdgcn_cvt_pkrtz(nf[14], 1.0f));
                *(int4v*)&xbuf[q][cb][lane * 8] = p0;
                *(int4v*)&xbuf[q][cb][lane * 8 + 4] = p1;
            }
        }

        for (int to = 32; to < 64; to += 4)
#pragma unroll
            for (int u = 0; u < 4; ++u) {
                const int t = tc + to + u;
                phase(0, hbA, xvA0, xvA1, hA, hr0, t);
                phase(1, hbB, xvB0, xvB1, hB, hr1, t);
            }
    }
    h_last[(size_t)b0 * HH + lane] = hA;
    h_last[(size_t)(b0 + 1) * HH + lane] = hB;
}

// Decoder: one 16x16x64 tile per wave (16 consecutive (b,t) rows of one batch).
// hs read: 2KB contiguous per wave; out store: 704B contiguous per tile.
__global__ __launch_bounds__(256) void rnn_decode(
    const _Float16* __restrict__ hs, const float* __restrict__ W_dec,
    const float* __restrict__ b_dec, float* __restrict__ out)
{
    __shared__ __align__(16) _Float16 wl[16 * HH];
    const int tid = threadIdx.x;
    for (int i = tid; i < 16 * HH; i += 256)
        wl[i] = (_Float16)((i < OO * HH) ? W_dec[i] : 0.0f);
    __syncthreads();

    const int lane = tid & 63;
    const int wid  = tid >> 6;
    const int col  = lane & 15;
    const int quad = lane >> 4;
    const float bd = (col < OO) ? b_dec[col] : 0.0f;

    half8 bf0 = *(const half8*)&wl[col * HH + quad * 8];
    half8 bf1 = *(const half8*)&wl[col * HH + 32 + quad * 8];

    const size_t tile = (size_t)blockIdx.x * 4 + wid;   // 0..32767
    const size_t btb = tile * 16;
    const _Float16* ap = hs + (btb + (size_t)col) * HH + quad * 8;
    half8 a0 = *(const half8*)ap;
    half8 a1 = *(const half8*)(ap + 32);

    floatx4 acc = {0.0f, 0.0f, 0.0f, 0.0f};
    acc = __builtin_amdgcn_mfma_f32_16x16x32_f16(a0, bf0, acc, 0, 0, 0);
    acc = __builtin_amdgcn_mfma_f32_16x16x32_f16(a1, bf1, acc, 0, 0, 0);

    if (col < OO) {
#pragma unroll
        for (int r = 0; r < 4; ++r) {
            const size_t row = btb + (size_t)(quad * 4 + r);
            out[row * OO + col] = fmaxf(acc[r] + bd, 0.0f);
        }
    }
}

extern "C" void kernel_launch(void* const* d_in, const int* in_sizes, int n_in,
                              void* d_out, int out_size, void* d_ws, size_t ws_size,
                              hipStream_t stream) {
    const float* x     = (const float*)d_in[0];
    const float* W_ih  = (const float*)d_in[1];
    const float* b_ih  = (const float*)d_in[2];
    const float* W_hh  = (const float*)d_in[3];
    const float* b_hh  = (const float*)d_in[4];
    const float* W_dec = (const float*)d_in[5];
    const float* b_dec = (const float*)d_in[6];

    float* out    = (float*)d_out;
    float* h_last = out + (size_t)BB * TT * OO;   // second tuple output
    _Float16* hs  = (_Float16*)d_ws;              // [B][T][H] f16, 64 MiB

    rnn_rec<<<BB / 2, 64, 0, stream>>>(x, W_ih, b_ih, W_hh, b_hh, hs, h_last);
    rnn_decode<<<8192, 256, 0, stream>>>(hs, W_dec, b_dec, out);
}